// Round 1
// baseline (579.236 us; speedup 1.0000x reference)
//
#include <hip/hip_runtime.h>
#include <math.h>

#define CRF_B 256
#define CRF_S 2048
#define CRF_K 64

// ws layout (floats):
//   pf   [B*K]      forward  p at t=1024
//   Cf   [B]        forward  log-scale
//   pb   [B*K]      backward p at t=1024
//   Cb   [B]        backward log-scale
//   loss [B]        per-batch losses
// total = 2*(B*K+B)+B floats = ~134 KB

__device__ __forceinline__ float waveMax(float v) {
#pragma unroll
    for (int k = 32; k >= 1; k >>= 1)
        v = fmaxf(v, __shfl_xor(v, k, 64));
    return v;
}

// Compiler-only fence. Blocks are a single wave: DS ops from one wave are
// processed in-order by the LDS pipe, so cross-lane write->read visibility
// needs no s_barrier and (critically) no vmcnt(0) drain that would kill the
// global prefetch pipeline. This only prevents compiler reordering.
__device__ __forceinline__ void lds_fence() { asm volatile("" ::: "memory"); }

__global__ __launch_bounds__(64) void crf_scan_kernel(
    const float* __restrict__ scores, const float* __restrict__ trans,
    const float* __restrict__ source, const float* __restrict__ sink,
    float* __restrict__ ws)
{
    const int lane = threadIdx.x;
    const bool fwd = blockIdx.x < CRF_B;
    const int b = fwd ? blockIdx.x : (blockIdx.x - CRF_B);

    __shared__ __align__(16) float sh[2][CRF_K];

    // E in registers: forward lane holds column `lane` of exp(T);
    // backward lane holds row `lane` of exp(T).
    float E[CRF_K];
    if (fwd) {
#pragma unroll
        for (int i = 0; i < CRF_K; ++i)
            E[i] = __expf(trans[i * CRF_K + lane]);
    } else {
        const float4* row = (const float4*)(trans + lane * CRF_K);
#pragma unroll
        for (int jj = 0; jj < CRF_K / 4; ++jj) {
            float4 t4 = row[jj];
            E[4 * jj + 0] = __expf(t4.x);
            E[4 * jj + 1] = __expf(t4.y);
            E[4 * jj + 2] = __expf(t4.z);
            E[4 * jj + 3] = __expf(t4.w);
        }
    }

    const float* sc = scores + (size_t)b * CRF_S * CRF_K + lane;

    float p, C;
    float buf[8];  // software prefetch pipeline, depth 8

    // dot(lane) = sum_i sh[kb][i] * E[i], LDS broadcast reads (b128)
    auto dot = [&](int kb) -> float {
        float a0 = 0.f, a1 = 0.f, a2 = 0.f, a3 = 0.f;
#pragma unroll
        for (int i = 0; i < CRF_K; i += 4) {
            const float4 pv = *(const float4*)&sh[kb][i];
            a0 = fmaf(pv.x, E[i + 0], a0);
            a1 = fmaf(pv.y, E[i + 1], a1);
            a2 = fmaf(pv.z, E[i + 2], a2);
            a3 = fmaf(pv.w, E[i + 3], a3);
        }
        return (a0 + a1) + (a2 + a3);
    };

    auto rescale = [&]() {
        const float m = waveMax(p);
        p *= 1.0f / m;
        C += __logf(m);
    };

    if (fwd) {
        // alpha_0 = source + s_0 ; 1024 steps t=1..1024
        const float a0 = source[lane] + sc[0];
        C = waveMax(a0);
        p = __expf(a0 - C);
#pragma unroll
        for (int k = 0; k < 8; ++k) buf[k] = sc[(1 + k) * CRF_K];
        for (int g = 0; g < 128; ++g) {
            const int tbase = 1 + g * 8;
#pragma unroll
            for (int k = 0; k < 8; ++k) {
                const float s = buf[k];
                // prefetch 8 steps ahead; max index t=1032 < 2048 (in-bounds, maybe unused)
                buf[k] = sc[(tbase + 8 + k) * CRF_K];
                sh[k & 1][lane] = p;
                lds_fence();
                const float q = dot(k & 1);
                lds_fence();
                p = q * __expf(s);
                if ((k & 3) == 3) rescale();
            }
        }
    } else {
        // beta_{2047} = sink ; 1023 steps, step n consumes s index (2047-n), n=0..1022
        const float b0 = sink[lane];
        C = waveMax(b0);
        p = __expf(b0 - C);
#pragma unroll
        for (int k = 0; k < 8; ++k) buf[k] = sc[(2047 - k) * CRF_K];
        for (int g = 0; g < 127; ++g) {
            const int nbase = g * 8;
#pragma unroll
            for (int k = 0; k < 8; ++k) {
                const float s = buf[k];
                // prefetch; min index 2047-1023 = 1024 >= 0 (in-bounds)
                buf[k] = sc[(2047 - (nbase + 8 + k)) * CRF_K];
                const float u = p * __expf(s);
                sh[k & 1][lane] = u;
                lds_fence();
                const float q = dot(k & 1);
                lds_fence();
                p = q;
                if ((k & 3) == 3) rescale();
            }
        }
        // epilogue: n = 1016..1022 (7 steps), buf[0..6] already prefetched
#pragma unroll
        for (int k = 0; k < 7; ++k) {
            const float s = buf[k];
            const float u = p * __expf(s);
            sh[k & 1][lane] = u;
            lds_fence();
            const float q = dot(k & 1);
            lds_fence();
            p = q;
            if ((k & 3) == 3) rescale();
        }
    }

    // final rescale so p <= 1 (prevents overflow in pf*pb combine)
    {
        const float m = waveMax(p);
        p *= 1.0f / m;
        C += __logf(m);
    }

    float* pf = ws;
    float* Cf = ws + CRF_B * CRF_K;
    float* pb = Cf + CRF_B;
    float* Cb = pb + CRF_B * CRF_K;
    if (fwd) {
        pf[b * CRF_K + lane] = p;
        if (lane == 0) Cf[b] = C;
    } else {
        pb[b * CRF_K + lane] = p;
        if (lane == 0) Cb[b] = C;
    }
}

__global__ __launch_bounds__(256) void crf_gold_combine_kernel(
    const float* __restrict__ scores, const int* __restrict__ states,
    const float* __restrict__ trans, const float* __restrict__ source,
    const float* __restrict__ sink, const float* __restrict__ ws,
    float* __restrict__ lossOut)
{
    const int b = blockIdx.x;
    const int tid = threadIdx.x;
    const float* pf = ws;
    const float* Cf = ws + CRF_B * CRF_K;
    const float* pb = Cf + CRF_B;
    const float* Cb = pb + CRF_B * CRF_K;

    __shared__ float red[256];

    // logZ_b = Cf + Cb + log( sum_i pf[i]*pb[i] )
    float v = (tid < CRF_K) ? pf[b * CRF_K + tid] * pb[b * CRF_K + tid] : 0.f;
    red[tid] = v;
    __syncthreads();
    for (int s2 = 128; s2 > 0; s2 >>= 1) {
        if (tid < s2) red[tid] += red[tid + s2];
        __syncthreads();
    }
    const float r1 = red[0];
    __syncthreads();

    // gold path score: emissions + transitions
    const int* st = states + (size_t)b * CRF_S;
    float g = 0.f;
    for (int t = tid; t < CRF_S; t += 256) {
        const int cur = st[t];
        g += scores[((size_t)b * CRF_S + t) * CRF_K + cur];
        if (t > 0) g += trans[st[t - 1] * CRF_K + cur];
    }
    red[tid] = g;
    __syncthreads();
    for (int s2 = 128; s2 > 0; s2 >>= 1) {
        if (tid < s2) red[tid] += red[tid + s2];
        __syncthreads();
    }
    if (tid == 0) {
        const float gold = source[st[0]] + red[0] + sink[st[CRF_S - 1]];
        lossOut[b] = (Cf[b] + Cb[b] + logf(r1)) - gold;
    }
}

__global__ __launch_bounds__(256) void crf_mean_kernel(
    const float* __restrict__ loss, float* __restrict__ out)
{
    __shared__ float red[256];
    const int tid = threadIdx.x;
    red[tid] = loss[tid];
    __syncthreads();
    for (int s2 = 128; s2 > 0; s2 >>= 1) {
        if (tid < s2) red[tid] += red[tid + s2];
        __syncthreads();
    }
    if (tid == 0) out[0] = red[0] * (1.0f / CRF_B);
}

extern "C" void kernel_launch(void* const* d_in, const int* in_sizes, int n_in,
                              void* d_out, int out_size, void* d_ws, size_t ws_size,
                              hipStream_t stream) {
    const float* scores = (const float*)d_in[0];
    const int*   states = (const int*)d_in[1];
    const float* trans  = (const float*)d_in[2];
    const float* source = (const float*)d_in[3];
    const float* sink   = (const float*)d_in[4];

    float* ws = (float*)d_ws;
    float* loss = ws + 2 * (CRF_B * CRF_K + CRF_B);
    float* out = (float*)d_out;

    crf_scan_kernel<<<2 * CRF_B, CRF_K, 0, stream>>>(scores, trans, source, sink, ws);
    crf_gold_combine_kernel<<<CRF_B, 256, 0, stream>>>(scores, states, trans, source, sink, ws, loss);
    crf_mean_kernel<<<1, 256, 0, stream>>>(loss, out);
}